// Round 4
// baseline (832.757 us; speedup 1.0000x reference)
//
#include <hip/hip_runtime.h>
#include <stdint.h>

#define FP8_MAX 448.0f

typedef float f32x4 __attribute__((ext_vector_type(4)));
typedef int i32x8 __attribute__((ext_vector_type(8)));
typedef int i32x4 __attribute__((ext_vector_type(4)));

// ---------- fp8 pack helper (HW RNE conversion, clamp to ±448 like the reference's clip) ----------
__device__ __forceinline__ unsigned int pack4_fp8(float4 v, float s) {
  float a = fminf(fmaxf(v.x * s, -FP8_MAX), FP8_MAX);
  float b = fminf(fmaxf(v.y * s, -FP8_MAX), FP8_MAX);
  float c = fminf(fmaxf(v.z * s, -FP8_MAX), FP8_MAX);
  float d = fminf(fmaxf(v.w * s, -FP8_MAX), FP8_MAX);
  unsigned int r = (unsigned int)__builtin_amdgcn_cvt_pk_fp8_f32(a, b, 0, false);
  r = (unsigned int)__builtin_amdgcn_cvt_pk_fp8_f32(c, d, (int)r, true);
  return r;
}

// ---------- async global->LDS 16B ----------
__device__ __forceinline__ void load16_to_lds(const void* g, void* l) {
  auto gp = (const __attribute__((address_space(1))) void*)(uintptr_t)g;
  auto lp = (__attribute__((address_space(3))) void*)(unsigned int)(uintptr_t)l;
  __builtin_amdgcn_global_load_lds(gp, lp, 16, 0, 0);
}

// ---------- fused per-tensor amax for x and w (one dispatch) ----------
__global__ void amax2_kernel(const float* __restrict__ x, int n4x,
                             const float* __restrict__ w, int n4w,
                             unsigned int* __restrict__ hdr) {
  const float4* p4;
  int n4, base, nblk;
  unsigned int* slot;
  if (blockIdx.x < 2048) {
    p4 = (const float4*)x; n4 = n4x; base = blockIdx.x; nblk = 2048; slot = hdr;
  } else {
    p4 = (const float4*)w; n4 = n4w; base = blockIdx.x - 2048; nblk = 512; slot = hdr + 1;
  }
  int i = base * blockDim.x + threadIdx.x;
  int stride = nblk * blockDim.x;
  float m = 0.0f;
  for (; i < n4; i += stride) {
    float4 v = p4[i];
    m = fmaxf(m, fmaxf(fmaxf(fabsf(v.x), fabsf(v.y)), fmaxf(fabsf(v.z), fabsf(v.w))));
  }
#pragma unroll
  for (int off = 32; off > 0; off >>= 1)
    m = fmaxf(m, __shfl_down(m, off, 64));
  __shared__ float wmax[4];
  int lane = threadIdx.x & 63;
  int wv = threadIdx.x >> 6;
  if (lane == 0) wmax[wv] = m;
  __syncthreads();
  if (threadIdx.x == 0) {
    m = fmaxf(fmaxf(wmax[0], wmax[1]), fmaxf(wmax[2], wmax[3]));
    atomicMax(slot, __float_as_uint(m));  // all values >=0: uint order == float order
  }
}

// ---------- quantize x: [M,K] fp32 -> [M,K] fp8 bytes ----------
__global__ void quant_x_kernel(const float* __restrict__ x, unsigned int* __restrict__ xq,
                               const unsigned int* __restrict__ hdr, int n4) {
  float s = FP8_MAX / fmaxf(__uint_as_float(hdr[0]), 1e-12f);
  int i = blockIdx.x * blockDim.x + threadIdx.x;
  int stride = gridDim.x * blockDim.x;
  const float4* x4 = (const float4*)x;
  for (; i < n4; i += stride)
    xq[i] = pack4_fp8(x4[i], s);
}

// ---------- quantize + transpose weight: [K,N] fp32 -> [N,K] fp8 bytes ----------
__global__ void quant_w_t_kernel(const float* __restrict__ w, unsigned char* __restrict__ wqT,
                                 const unsigned int* __restrict__ hdr, int K, int N) {
  __shared__ unsigned int tileT[64][17];  // [n][k-word], +1 word pad
  float s = FP8_MAX / fmaxf(__uint_as_float(hdr[1]), 1e-12f);
  int tk0 = blockIdx.y << 6;
  int tn0 = blockIdx.x << 6;
  int t = threadIdx.x;

  int rn = (t & 15) << 2;   // n within tile; adjacent lanes -> adjacent 16B => coalesced reads
  int rk = (t >> 4) << 2;   // k within tile
  unsigned int wrow[4];
#pragma unroll
  for (int j = 0; j < 4; ++j) {
    float4 v = *(const float4*)(w + (size_t)(tk0 + rk + j) * N + tn0 + rn);
    wrow[j] = pack4_fp8(v, s);  // bytes = cols n..n+3 of row k+j
  }
#pragma unroll
  for (int i = 0; i < 4; ++i) {
    unsigned int colw = ((wrow[0] >> (8 * i)) & 0xffu)
                      | (((wrow[1] >> (8 * i)) & 0xffu) << 8)
                      | (((wrow[2] >> (8 * i)) & 0xffu) << 16)
                      | (((wrow[3] >> (8 * i)) & 0xffu) << 24);
    tileT[rn + i][rk >> 2] = colw;  // bytes = rows k..k+3 of col n+i
  }
  __syncthreads();

  int n = t >> 2;
  int kc = (t & 3) << 2;  // word index within row
  uint4 v = make_uint4(tileT[n][kc], tileT[n][kc + 1], tileT[n][kc + 2], tileT[n][kc + 3]);
  *(uint4*)(wqT + (size_t)(tn0 + n) * K + tk0 + (kc << 2)) = v;
}

// ---------- helpers for the phased GEMM ----------
__device__ __forceinline__ i32x8 read_frag(const unsigned char* p, int off0) {
  i32x4 lo = *(const i32x4*)(p + off0);
  i32x4 hi = *(const i32x4*)(p + (off0 ^ 16));
  return __builtin_shufflevector(lo, hi, 0, 1, 2, 3, 4, 5, 6, 7);
}

#define MFMA1(a, b, c) \
  __builtin_amdgcn_mfma_scale_f32_16x16x128_f8f6f4(a, b, c, 0, 0, 0, 0x7f7f7f7f, 0, 0x7f7f7f7f)

// one C-quadrant: 4 M-frags (AF_) x 2 N-frags (BF_) -> acc[M0_..M0_+3][N0_..N0_+1]
#define MFMA_Q(AF_, BF_, M0_, N0_)                                          \
  do {                                                                      \
    __builtin_amdgcn_s_setprio(1);                                          \
    acc[M0_ + 0][N0_ + 0] = MFMA1(AF_[0], BF_[0], acc[M0_ + 0][N0_ + 0]);   \
    acc[M0_ + 0][N0_ + 1] = MFMA1(AF_[0], BF_[1], acc[M0_ + 0][N0_ + 1]);   \
    acc[M0_ + 1][N0_ + 0] = MFMA1(AF_[1], BF_[0], acc[M0_ + 1][N0_ + 0]);   \
    acc[M0_ + 1][N0_ + 1] = MFMA1(AF_[1], BF_[1], acc[M0_ + 1][N0_ + 1]);   \
    acc[M0_ + 2][N0_ + 0] = MFMA1(AF_[2], BF_[0], acc[M0_ + 2][N0_ + 0]);   \
    acc[M0_ + 2][N0_ + 1] = MFMA1(AF_[2], BF_[1], acc[M0_ + 2][N0_ + 1]);   \
    acc[M0_ + 3][N0_ + 0] = MFMA1(AF_[3], BF_[0], acc[M0_ + 3][N0_ + 0]);   \
    acc[M0_ + 3][N0_ + 1] = MFMA1(AF_[3], BF_[1], acc[M0_ + 3][N0_ + 1]);   \
    __builtin_amdgcn_s_setprio(0);                                          \
  } while (0)

#define BAR() __builtin_amdgcn_s_barrier()
#define SCHED0() __builtin_amdgcn_sched_barrier(0)
#define LGKMC(N_)                                              \
  do {                                                         \
    asm volatile("s_waitcnt lgkmcnt(" #N_ ")" ::: "memory");   \
    __builtin_amdgcn_sched_barrier(0);                         \
  } while (0)
#define VMCNT(N_)                                               \
  do {                                                          \
    asm volatile("s_waitcnt vmcnt(" #N_ ")" ::: "memory");      \
    __builtin_amdgcn_sched_barrier(0);                          \
  } while (0)

// ---------- fp8 GEMM, 256x256 tile, 8-wave, 4-phase/K-tile, fully pipelined ----------
// MX-scaled K=128 MFMA (identity e8m0 scales). LDS: 2 dbuf x (A 32KB + B 32KB) = 128 KB.
// vmcnt ledger (per wave, 2 loads/stage): steady in-flight at P4 = 12; VMCNT(4)
// retires all 8 of tile t+1, leaves t+2's 4 in flight. Never 0 in main loop.
// lgkm ledger (ds_read_b128 counted, in-order): frags read ONE PHASE AHEAD --
//   P4 tail (after vmcnt+bar): issue afA',bfA' of next tile (12 rds)
//   P1: issue bfB (4) then SCHED0 then afB (8); wait lgkm(12) -> afA,bfA ready; Q1
//   P2: wait lgkm(8)  -> bfB ready; Q2
//   P3: wait lgkm(0)  -> afB ready; Q3
//   P4: no wait; Q4
// so ds_read bandwidth hides under the previous phase's MFMA instead of serializing.
// Stage-overwrite safety (audited): every LDS region has all reader-waves drained
// (counted lgkm) + a barrier before its next stage is issued.
__global__ __launch_bounds__(512, 2) void gemm_fp8_kernel(
    const unsigned char* __restrict__ Aq,   // [M,K] fp8
    const unsigned char* __restrict__ Bq,   // [N,K] fp8 (w transposed)
    const unsigned int* __restrict__ hdr,
    float* __restrict__ out, int M, int N, int K) {
  __shared__ __align__(16) unsigned char smem[131072];  // A: [0,64K), B: [64K,128K)

  const int t = threadIdx.x;
  const int wave = t >> 6;
  const int lane = t & 63;
  const int row16 = lane & 15;
  const int quad = lane >> 4;
  const int wr = wave >> 2;           // 0..1  (M-half of the 256 rows)
  const int wc = wave & 3;            // 0..3  (N-quarter)
  const int m0 = blockIdx.y << 8;
  const int n0 = blockIdx.x << 8;

  // ---- staging geometry: per call a wave writes 8 rows x 128B (lane-linear in LDS).
  // Global source chunk pre-swizzled: physical chunk p of row r holds logical p^(r&7).
  const int sRow = (wave << 3) + (lane >> 3);                 // 0..63
  const int sCol = (((lane & 7) ^ (lane >> 3)) << 4);         // inverse-swizzled source
  const unsigned char* agBase = Aq + (size_t)(m0 + sRow) * K + sCol;
  const unsigned char* bgBase = Bq + (size_t)(n0 + sRow) * K + sCol;
  const int ldsStageOff = (wave << 10) + (lane << 4);

  auto stageA = [&](int u, int h) {  // half h (128 rows) of K-tile u -> A region
    const int buf = (u & 1) << 15;
#pragma unroll
    for (int r = 0; r < 2; ++r)
      load16_to_lds(agBase + (size_t)((h << 7) + (r << 6)) * K + ((size_t)u << 7),
                    smem + buf + (h << 14) + (r << 13) + ldsStageOff);
  };
  auto stageB = [&](int u, int h) {
    const int buf = (u & 1) << 15;
#pragma unroll
    for (int r = 0; r < 2; ++r)
      load16_to_lds(bgBase + (size_t)((h << 7) + (r << 6)) * K + ((size_t)u << 7),
                    smem + 65536 + buf + (h << 14) + (r << 13) + ldsStageOff);
  };

  // ---- fragment addressing: lane holds row (lane&15), k-bytes quad*32..+31 =
  // logical chunks {2q,2q+1}; physical = logical ^ (row&7).
  const int off0 = (((quad << 1) ^ (row16 & 7)) << 4);        // second 16B at off0^16
  const int aRow = (wr << 7) + row16;                         // + mi*16
  const int bRow = (wc << 6) + row16;                         // + ni*16

  f32x4 acc[8][4] = {};
  i32x8 afA[4], afB[4], bfA[2], bfB[2];

  const int NT = K >> 7;  // 128B K-tiles (=32)

  // ---- prologue: stage tile0 fully + tile1's half-0 pair; retire tile0; prefetch frags
  stageA(0, 0); stageA(0, 1); stageB(0, 0); stageB(0, 1);
  stageB(1, 0); stageA(1, 0);
  VMCNT(4);            // tile0 resident; tile1's 4 loads stay in flight
  BAR();
#pragma unroll
  for (int i = 0; i < 4; ++i)
    afA[i] = read_frag(smem + ((aRow + i * 16) << 7), off0);
  bfA[0] = read_frag(smem + 65536 + ((bRow + 0) << 7), off0);
  bfA[1] = read_frag(smem + 65536 + ((bRow + 16) << 7), off0);
  // 12 ds_reads outstanding entering the loop (drained by P1's lgkm(12))

  auto tile_body = [&](int tt, bool stg1, bool stg2, int waitN, bool pref) {
    const int buf = (tt & 1) << 15;
    const unsigned char* Ab = smem + buf;
    const unsigned char* Bb = smem + 65536 + buf;
    // -------- P1: issue bfB then afB; compute Q1 = afA x bfA
    bfB[0] = read_frag(Bb + ((bRow + 32) << 7), off0);
    bfB[1] = read_frag(Bb + ((bRow + 48) << 7), off0);
    SCHED0();  // pin bfB-before-afB issue order (lgkm counts are positional)
    afB[0] = read_frag(Ab + ((aRow + 64) << 7), off0);
    afB[1] = read_frag(Ab + ((aRow + 80) << 7), off0);
    afB[2] = read_frag(Ab + ((aRow + 96) << 7), off0);
    afB[3] = read_frag(Ab + ((aRow + 112) << 7), off0);
    if (stg1) stageA(tt + 1, 1);
    BAR();
    LGKMC(12);                     // afA, bfA ready (issued last phase)
    MFMA_Q(afA, bfA, 0, 0);
    BAR();
    // -------- P2: Q2 = afA x bfB
    if (stg1) stageB(tt + 1, 1);
    BAR();
    LGKMC(8);                      // bfB ready
    MFMA_Q(afA, bfB, 0, 2);
    BAR();
    // -------- P3: Q3 = afB x bfA
    if (stg2) stageB(tt + 2, 0);
    BAR();
    LGKMC(0);                      // afB ready
    MFMA_Q(afB, bfA, 4, 0);
    BAR();
    // -------- P4: retire next tile's staging, prefetch its afA/bfA, Q4 = afB x bfB
    if (stg2) stageA(tt + 2, 0);
    if (waitN == 4) {
      VMCNT(4);   // tile t+1 resident; tile t+2's 2 half-tiles stay in flight
    } else if (waitN == 0) {
      VMCNT(0);   // penultimate tile: drain the final tile's loads
    }
    BAR();
    if (pref) {
      const unsigned char* An = smem + (buf ^ 32768);
      const unsigned char* Bn = smem + 65536 + (buf ^ 32768);
      afA[0] = read_frag(An + ((aRow + 0) << 7), off0);
      afA[1] = read_frag(An + ((aRow + 16) << 7), off0);
      afA[2] = read_frag(An + ((aRow + 32) << 7), off0);
      afA[3] = read_frag(An + ((aRow + 48) << 7), off0);
      bfA[0] = read_frag(Bn + ((bRow + 0) << 7), off0);
      bfA[1] = read_frag(Bn + ((bRow + 16) << 7), off0);
    }
    MFMA_Q(afB, bfB, 4, 2);        // no wait: afB/bfB drained at P3
    BAR();
  };

  for (int tt = 0; tt < NT - 2; ++tt) tile_body(tt, true, true, 4, true);
  tile_body(NT - 2, true, false, 0, true);
  tile_body(NT - 1, false, false, -1, false);

  // ---- epilogue: dequant scale = (amax_x/448)*(amax_w/448)
  const float ax = fmaxf(__uint_as_float(hdr[0]), 1e-12f);
  const float aw = fmaxf(__uint_as_float(hdr[1]), 1e-12f);
  const float sc = (ax / FP8_MAX) * (aw / FP8_MAX);
#pragma unroll
  for (int mi = 0; mi < 8; ++mi) {
#pragma unroll
    for (int ni = 0; ni < 4; ++ni) {
      const int gc = n0 + (wc << 6) + ni * 16 + row16;
#pragma unroll
      for (int r = 0; r < 4; ++r) {
        const int gr = m0 + (wr << 7) + mi * 16 + quad * 4 + r;
        out[(size_t)gr * N + gc] = acc[mi][ni][r] * sc;  // C/D: col=lane&15, row=quad*4+reg
      }
    }
  }
}

extern "C" void kernel_launch(void* const* d_in, const int* in_sizes, int n_in,
                              void* d_out, int out_size, void* d_ws, size_t ws_size,
                              hipStream_t stream) {
  const float* x = (const float*)d_in[0];       // [M,K] fp32 (flattened [8,2048,4096])
  const float* w = (const float*)d_in[1];       // [K,N] fp32
  float* out = (float*)d_out;

  const int K = 4096;
  const int N = 4096;
  const int M = in_sizes[0] / K;                // 16384

  // workspace layout: [0..16) amax slots (uint bits), then xq [M*K], then wqT [N*K]
  unsigned int* hdr = (unsigned int*)d_ws;
  unsigned char* xq = (unsigned char*)d_ws + 16;
  unsigned char* wqT = xq + (size_t)M * K;

  hipMemsetAsync(d_ws, 0, 16, stream);  // zero amax slots (ws is poisoned each call)

  amax2_kernel<<<2560, 256, 0, stream>>>(x, (int)((size_t)M * K / 4), w,
                                         (int)((size_t)K * N / 4), hdr);

  quant_x_kernel<<<4096, 256, 0, stream>>>(x, (unsigned int*)xq, hdr, (int)((size_t)M * K / 4));
  quant_w_t_kernel<<<dim3(N / 64, K / 64), 256, 0, stream>>>(w, wqT, hdr, K, N);

  gemm_fp8_kernel<<<dim3(N / 256, M / 256), 512, 0, stream>>>(xq, wqT, hdr, out, M, N, K);
}

// Round 5
// 797.039 us; speedup vs baseline: 1.0448x; 1.0448x over previous
//
#include <hip/hip_runtime.h>
#include <stdint.h>

#define FP8_MAX 448.0f

typedef float f32x4 __attribute__((ext_vector_type(4)));
typedef int i32x8 __attribute__((ext_vector_type(8)));
typedef int i32x4 __attribute__((ext_vector_type(4)));

// ---------- fp8 pack helper (HW RNE conversion, clamp to ±448 like the reference's clip) ----------
__device__ __forceinline__ unsigned int pack4_fp8(float4 v, float s) {
  float a = fminf(fmaxf(v.x * s, -FP8_MAX), FP8_MAX);
  float b = fminf(fmaxf(v.y * s, -FP8_MAX), FP8_MAX);
  float c = fminf(fmaxf(v.z * s, -FP8_MAX), FP8_MAX);
  float d = fminf(fmaxf(v.w * s, -FP8_MAX), FP8_MAX);
  unsigned int r = (unsigned int)__builtin_amdgcn_cvt_pk_fp8_f32(a, b, 0, false);
  r = (unsigned int)__builtin_amdgcn_cvt_pk_fp8_f32(c, d, (int)r, true);
  return r;
}

// ---------- async global->LDS 16B ----------
__device__ __forceinline__ void load16_to_lds(const void* g, void* l) {
  auto gp = (const __attribute__((address_space(1))) void*)(uintptr_t)g;
  auto lp = (__attribute__((address_space(3))) void*)(unsigned int)(uintptr_t)l;
  __builtin_amdgcn_global_load_lds(gp, lp, 16, 0, 0);
}

__device__ __forceinline__ float amax4(float4 v) {
  return fmaxf(fmaxf(fabsf(v.x), fabsf(v.y)), fmaxf(fabsf(v.z), fabsf(v.w)));
}

// ---------- fused per-tensor amax for x and w, 4-deep MLP unroll ----------
// Grid-stride with ONE load in flight is latency-bound (Little's law: need ~2.4 MB
// in flight for 6.3 TB/s); unroll-4 issues 4 independent float4 loads per iter.
__global__ void amax2_kernel(const float* __restrict__ x, int n4x,
                             const float* __restrict__ w, int n4w,
                             unsigned int* __restrict__ hdr) {
  const float4* p4;
  int n4, base, nblk;
  unsigned int* slot;
  if (blockIdx.x < 2048) {
    p4 = (const float4*)x; n4 = n4x; base = blockIdx.x; nblk = 2048; slot = hdr;
  } else {
    p4 = (const float4*)w; n4 = n4w; base = blockIdx.x - 2048; nblk = 512; slot = hdr + 1;
  }
  int stride = nblk * blockDim.x;
  int i = base * blockDim.x + threadIdx.x;
  float m = 0.0f;
  for (; i + 3 * stride < n4; i += 4 * stride) {
    float4 v0 = p4[i];
    float4 v1 = p4[i + stride];
    float4 v2 = p4[i + 2 * stride];
    float4 v3 = p4[i + 3 * stride];
    m = fmaxf(m, fmaxf(fmaxf(amax4(v0), amax4(v1)), fmaxf(amax4(v2), amax4(v3))));
  }
  for (; i < n4; i += stride) m = fmaxf(m, amax4(p4[i]));
#pragma unroll
  for (int off = 32; off > 0; off >>= 1)
    m = fmaxf(m, __shfl_down(m, off, 64));
  __shared__ float wmax[4];
  int lane = threadIdx.x & 63;
  int wv = threadIdx.x >> 6;
  if (lane == 0) wmax[wv] = m;
  __syncthreads();
  if (threadIdx.x == 0) {
    m = fmaxf(fmaxf(wmax[0], wmax[1]), fmaxf(wmax[2], wmax[3]));
    atomicMax(slot, __float_as_uint(m));  // all values >=0: uint order == float order
  }
}

// ---------- fused quantize: x -> xq (blocks 0..2047) and w -> wqT (blocks 2048..6143) ----------
// x part: 64B/lane/iter loads (4 float4), uint4 (16B) stores -- 4-deep MLP, bytes identical
// to the scalar version. w part: identical math to the old quant_w_t, grid flattened.
__global__ void quant_fused_kernel(const float* __restrict__ x, unsigned int* __restrict__ xq,
                                   int n16x,
                                   const float* __restrict__ w, unsigned char* __restrict__ wqT,
                                   int K, int N, const unsigned int* __restrict__ hdr) {
  __shared__ unsigned int tileT[64][17];  // only used by w-blocks
  if (blockIdx.x < 2048) {
    float s = FP8_MAX / fmaxf(__uint_as_float(hdr[0]), 1e-12f);
    const float4* x4 = (const float4*)x;
    uint4* o4 = (uint4*)xq;
    int stride = 2048 * blockDim.x;
    for (int i = blockIdx.x * blockDim.x + threadIdx.x; i < n16x; i += stride) {
      float4 a = x4[4 * i + 0];
      float4 b = x4[4 * i + 1];
      float4 c = x4[4 * i + 2];
      float4 d = x4[4 * i + 3];
      o4[i] = make_uint4(pack4_fp8(a, s), pack4_fp8(b, s), pack4_fp8(c, s), pack4_fp8(d, s));
    }
  } else {
    float s = FP8_MAX / fmaxf(__uint_as_float(hdr[1]), 1e-12f);
    int bx = blockIdx.x - 2048;
    int tn0 = (bx & 63) << 6;
    int tk0 = (bx >> 6) << 6;
    int t = threadIdx.x;

    int rn = (t & 15) << 2;   // n within tile; adjacent lanes -> adjacent 16B => coalesced
    int rk = (t >> 4) << 2;   // k within tile
    unsigned int wrow[4];
#pragma unroll
    for (int j = 0; j < 4; ++j) {
      float4 v = *(const float4*)(w + (size_t)(tk0 + rk + j) * N + tn0 + rn);
      wrow[j] = pack4_fp8(v, s);  // bytes = cols n..n+3 of row k+j
    }
#pragma unroll
    for (int i = 0; i < 4; ++i) {
      unsigned int colw = ((wrow[0] >> (8 * i)) & 0xffu)
                        | (((wrow[1] >> (8 * i)) & 0xffu) << 8)
                        | (((wrow[2] >> (8 * i)) & 0xffu) << 16)
                        | (((wrow[3] >> (8 * i)) & 0xffu) << 24);
      tileT[rn + i][rk >> 2] = colw;  // bytes = rows k..k+3 of col n+i
    }
    __syncthreads();

    int n = t >> 2;
    int kc = (t & 3) << 2;  // word index within row
    uint4 v = make_uint4(tileT[n][kc], tileT[n][kc + 1], tileT[n][kc + 2], tileT[n][kc + 3]);
    *(uint4*)(wqT + (size_t)(tn0 + n) * K + tk0 + (kc << 2)) = v;
  }
}

// ---------- helpers for the phased GEMM ----------
__device__ __forceinline__ i32x8 read_frag(const unsigned char* p, int off0) {
  i32x4 lo = *(const i32x4*)(p + off0);
  i32x4 hi = *(const i32x4*)(p + (off0 ^ 16));
  return __builtin_shufflevector(lo, hi, 0, 1, 2, 3, 4, 5, 6, 7);
}

#define MFMA1(a, b, c) \
  __builtin_amdgcn_mfma_scale_f32_16x16x128_f8f6f4(a, b, c, 0, 0, 0, 0x7f7f7f7f, 0, 0x7f7f7f7f)

// one C-quadrant: 4 M-frags x 2 N-frags, all-literal acc indices (no scratch)
#define MFMA_Q(M0_, N0_)                                              \
  do {                                                                \
    __builtin_amdgcn_s_setprio(1);                                    \
    acc[M0_ + 0][N0_ + 0] = MFMA1(af[0], bf[N0_ + 0], acc[M0_ + 0][N0_ + 0]); \
    acc[M0_ + 0][N0_ + 1] = MFMA1(af[0], bf[N0_ + 1], acc[M0_ + 0][N0_ + 1]); \
    acc[M0_ + 1][N0_ + 0] = MFMA1(af[1], bf[N0_ + 0], acc[M0_ + 1][N0_ + 0]); \
    acc[M0_ + 1][N0_ + 1] = MFMA1(af[1], bf[N0_ + 1], acc[M0_ + 1][N0_ + 1]); \
    acc[M0_ + 2][N0_ + 0] = MFMA1(af[2], bf[N0_ + 0], acc[M0_ + 2][N0_ + 0]); \
    acc[M0_ + 2][N0_ + 1] = MFMA1(af[2], bf[N0_ + 1], acc[M0_ + 2][N0_ + 1]); \
    acc[M0_ + 3][N0_ + 0] = MFMA1(af[3], bf[N0_ + 0], acc[M0_ + 3][N0_ + 0]); \
    acc[M0_ + 3][N0_ + 1] = MFMA1(af[3], bf[N0_ + 1], acc[M0_ + 3][N0_ + 1]); \
    __builtin_amdgcn_s_setprio(0);                                    \
  } while (0)

#define BAR() __builtin_amdgcn_s_barrier()
#define LGKM0()                                           \
  do {                                                    \
    asm volatile("s_waitcnt lgkmcnt(0)" ::: "memory");    \
    __builtin_amdgcn_sched_barrier(0);                    \
  } while (0)
#define VMCNT(N_)                                               \
  do {                                                          \
    asm volatile("s_waitcnt vmcnt(" #N_ ")" ::: "memory");      \
    __builtin_amdgcn_sched_barrier(0);                          \
  } while (0)

// ---------- fp8 GEMM, 256x256 tile, 8-wave, 4-phase/K-tile counted-vmcnt schedule ----------
// (round-3 configuration, measured 315.7 us / MfmaUtil 38% -- round-4's cross-phase
// fragment pipeline regressed to 344 us and was reverted.)
// MX-scaled K=128 MFMA (identity e8m0 scales). LDS: 2 dbuf x (A 32KB + B 32KB) = 128 KB.
// Per K-tile t (buf = t&1): 4 phases, each = {ds_read frags | stage one half-tile (2
// global_load_lds) | s_barrier | lgkmcnt(0) | setprio(1) 8xMFMA setprio(0) | s_barrier}.
// Stage slots: A1(t+1)@ph1, B1(t+1)@ph2, B0(t+2)@ph3, A0(t+2)@ph4 (each freed by the
// preceding phase's end barrier). One s_waitcnt vmcnt(4) per K-tile at ph4 -- never 0
// in the main loop.
__global__ __launch_bounds__(512, 2) void gemm_fp8_kernel(
    const unsigned char* __restrict__ Aq,   // [M,K] fp8
    const unsigned char* __restrict__ Bq,   // [N,K] fp8 (w transposed)
    const unsigned int* __restrict__ hdr,
    float* __restrict__ out, int M, int N, int K) {
  __shared__ __align__(16) unsigned char smem[131072];  // A: [0,64K), B: [64K,128K)

  const int t = threadIdx.x;
  const int wave = t >> 6;
  const int lane = t & 63;
  const int row16 = lane & 15;
  const int quad = lane >> 4;
  const int wr = wave >> 2;           // 0..1  (M-half of the 256 rows)
  const int wc = wave & 3;            // 0..3  (N-quarter)
  const int m0 = blockIdx.y << 8;
  const int n0 = blockIdx.x << 8;

  // ---- staging geometry: per call a wave writes 8 rows x 128B (lane-linear in LDS).
  // Global source chunk pre-swizzled: physical chunk p of row r holds logical p^(r&7).
  const int sRow = (wave << 3) + (lane >> 3);                 // 0..63
  const int sCol = (((lane & 7) ^ (lane >> 3)) << 4);         // inverse-swizzled source
  const unsigned char* agBase = Aq + (size_t)(m0 + sRow) * K + sCol;
  const unsigned char* bgBase = Bq + (size_t)(n0 + sRow) * K + sCol;
  const int ldsStageOff = (wave << 10) + (lane << 4);

  auto stageA = [&](int u, int h) {  // half h (128 rows) of K-tile u -> A region
    const int buf = (u & 1) << 15;
#pragma unroll
    for (int r = 0; r < 2; ++r)
      load16_to_lds(agBase + (size_t)((h << 7) + (r << 6)) * K + ((size_t)u << 7),
                    smem + buf + (h << 14) + (r << 13) + ldsStageOff);
  };
  auto stageB = [&](int u, int h) {
    const int buf = (u & 1) << 15;
#pragma unroll
    for (int r = 0; r < 2; ++r)
      load16_to_lds(bgBase + (size_t)((h << 7) + (r << 6)) * K + ((size_t)u << 7),
                    smem + 65536 + buf + (h << 14) + (r << 13) + ldsStageOff);
  };

  // ---- fragment addressing: lane holds row (lane&15), k-bytes quad*32..+31 =
  // logical chunks {2q,2q+1}; physical = logical ^ (row&7).
  const int off0 = (((quad << 1) ^ (row16 & 7)) << 4);        // second 16B at off0^16
  const int aRow = (wr << 7) + row16;                         // + mi*16
  const int bRow = (wc << 6) + row16;                         // + ni*16

  f32x4 acc[8][4] = {};

  const int NT = K >> 7;  // 128B K-tiles (=32)

  // ---- prologue: tile0 fully + A0,B0 of tile1; wait leaves tile1's 4 loads in flight
  stageA(0, 0); stageA(0, 1); stageB(0, 0); stageB(0, 1);
  stageA(1, 0); stageB(1, 0);
  VMCNT(4);
  BAR();

  auto tile_body = [&](int tt, bool stg1, bool stg2, int waitN) {
    const int buf = (tt & 1) << 15;
    const unsigned char* Ab = smem + buf;
    const unsigned char* Bb = smem + 65536 + buf;
    i32x8 af[4], bf[4];
    // -------- phase 1: quadrant (M rows +0..63, N cols +0..31)
    af[0] = read_frag(Ab + ((aRow + 0) << 7), off0);
    af[1] = read_frag(Ab + ((aRow + 16) << 7), off0);
    af[2] = read_frag(Ab + ((aRow + 32) << 7), off0);
    af[3] = read_frag(Ab + ((aRow + 48) << 7), off0);
    bf[0] = read_frag(Bb + ((bRow + 0) << 7), off0);
    bf[1] = read_frag(Bb + ((bRow + 16) << 7), off0);
    if (stg1) stageA(tt + 1, 1);
    BAR();
    LGKM0();
    MFMA_Q(0, 0);
    BAR();
    // -------- phase 2: (+0..63, +32..63)
    bf[2] = read_frag(Bb + ((bRow + 32) << 7), off0);
    bf[3] = read_frag(Bb + ((bRow + 48) << 7), off0);
    if (stg1) stageB(tt + 1, 1);
    BAR();
    LGKM0();
    MFMA_Q(0, 2);
    BAR();
    // -------- phase 3: (+64..127, +0..31)
    af[0] = read_frag(Ab + ((aRow + 64) << 7), off0);
    af[1] = read_frag(Ab + ((aRow + 80) << 7), off0);
    af[2] = read_frag(Ab + ((aRow + 96) << 7), off0);
    af[3] = read_frag(Ab + ((aRow + 112) << 7), off0);
    if (stg2) stageB(tt + 2, 0);
    BAR();
    LGKM0();
    MFMA_Q(4, 0);
    BAR();
    // -------- phase 4: (+64..127, +32..63)
    if (stg2) stageA(tt + 2, 0);
    if (waitN == 4) {
      VMCNT(4);   // next tile resident; 2 half-tiles stay in flight
    } else if (waitN == 0) {
      VMCNT(0);   // penultimate tile: drain the last tile's loads
    }
    BAR();
    MFMA_Q(4, 2);
    BAR();
  };

  for (int tt = 0; tt < NT - 2; ++tt) tile_body(tt, true, true, 4);
  tile_body(NT - 2, true, false, 0);
  tile_body(NT - 1, false, false, -1);

  // ---- epilogue: dequant scale = (amax_x/448)*(amax_w/448)
  const float ax = fmaxf(__uint_as_float(hdr[0]), 1e-12f);
  const float aw = fmaxf(__uint_as_float(hdr[1]), 1e-12f);
  const float sc = (ax / FP8_MAX) * (aw / FP8_MAX);
#pragma unroll
  for (int mi = 0; mi < 8; ++mi) {
#pragma unroll
    for (int ni = 0; ni < 4; ++ni) {
      const int gc = n0 + (wc << 6) + ni * 16 + row16;
#pragma unroll
      for (int r = 0; r < 4; ++r) {
        const int gr = m0 + (wr << 7) + mi * 16 + quad * 4 + r;
        out[(size_t)gr * N + gc] = acc[mi][ni][r] * sc;  // C/D: col=lane&15, row=quad*4+reg
      }
    }
  }
}

extern "C" void kernel_launch(void* const* d_in, const int* in_sizes, int n_in,
                              void* d_out, int out_size, void* d_ws, size_t ws_size,
                              hipStream_t stream) {
  const float* x = (const float*)d_in[0];       // [M,K] fp32 (flattened [8,2048,4096])
  const float* w = (const float*)d_in[1];       // [K,N] fp32
  float* out = (float*)d_out;

  const int K = 4096;
  const int N = 4096;
  const int M = in_sizes[0] / K;                // 16384

  // workspace layout: [0..16) amax slots (uint bits), then xq [M*K], then wqT [N*K]
  unsigned int* hdr = (unsigned int*)d_ws;
  unsigned char* xq = (unsigned char*)d_ws + 16;
  unsigned char* wqT = xq + (size_t)M * K;

  hipMemsetAsync(d_ws, 0, 16, stream);  // zero amax slots (ws is poisoned each call)

  amax2_kernel<<<2560, 256, 0, stream>>>(x, (int)((size_t)M * K / 4), w,
                                         (int)((size_t)K * N / 4), hdr);

  quant_fused_kernel<<<2048 + 4096, 256, 0, stream>>>(
      x, (unsigned int*)xq, (int)((size_t)M * K / 16), w, wqT, K, N, hdr);

  gemm_fp8_kernel<<<dim3(N / 256, M / 256), 512, 0, stream>>>(xq, wqT, hdr, out, M, N, K);
}